// Round 6
// baseline (102.914 us; speedup 1.0000x reference)
//
#include <hip/hip_runtime.h>
#include <hip/hip_fp16.h>

#define N 2048
#define ONW 4096
#define TW 128                        // tile width (pixels)
#define TH 32                         // tile height (pixels)
#define LUT_ENTRIES 12288
#define LUT_BYTES (LUT_ENTRIES * 8)   // 98304
#define SMEM_BYTES LUT_BYTES          // LUT only; halo staging removed

typedef _Float16 half4v __attribute__((ext_vector_type(4)));
typedef float fvec4 __attribute__((ext_vector_type(4)));

__device__ __forceinline__ int reflect(int i) {
    i = i < 0 ? -i : i;
    return i >= N ? 2 * N - 2 - i : i;
}

// compute the 12 LUT indices for one output pixel (pi,pj); fully
// constant-folds when called with literal pi/pj under unrolled loops
__device__ __forceinline__ void calc_idx(const int n[6][6], int pi, int pj, int* idx)
{
    const int bo[3][2] = {{0, 1}, {1, 1}, {1, 2}};
    const int co[3][2] = {{0, 2}, {2, 2}, {2, 1}};
    const int a8 = n[2 + pi][2 + pj] << 8;
    #pragma unroll
    for (int r = 0; r < 4; ++r) {
        #pragma unroll
        for (int k = 0; k < 3; ++k) {
            const int bp = bo[k][0], bq = bo[k][1];
            const int cp = co[k][0], cq = co[k][1];
            const int bdi = (r == 0) ? bp : (r == 1) ? bq : (r == 2) ? -bp : -bq;
            const int bdj = (r == 0) ? bq : (r == 1) ? -bp : (r == 2) ? -bq : bp;
            const int cdi = (r == 0) ? cp : (r == 1) ? cq : (r == 2) ? -cp : -cq;
            const int cdj = (r == 0) ? cq : (r == 1) ? -cp : (r == 2) ? -cq : cp;
            const int bv = n[pi + 2 + bdi][pj + 2 + bdj];
            const int cv = n[pi + 2 + cdi][pj + 2 + cdj];
            idx[r * 3 + k] = (k * 4096 + a8) + (bv * 16 + cv);
        }
    }
}

// sum the 3 k-terms per rotation and scatter into the 2x2 sub-pixel acc
__device__ __forceinline__ void consume(const half4v* v, float* o)
{
    #pragma unroll
    for (int r = 0; r < 4; ++r) {
        half4v S = v[3 * r] + v[3 * r + 1] + v[3 * r + 2];
        const float x = (float)S.x, y = (float)S.y;
        const float z = (float)S.z, w = (float)S.w;
        if (r == 0)      { o[0] += x; o[1] += y; o[2] += z; o[3] += w; }
        else if (r == 1) { o[0] += z; o[1] += x; o[2] += w; o[3] += y; }
        else if (r == 2) { o[0] += w; o[1] += z; o[2] += y; o[3] += x; }
        else             { o[0] += y; o[1] += w; o[2] += x; o[3] += z; }
    }
}

__global__ __launch_bounds__(1024, 4) void hdblut_kernel(
    const int* __restrict__ img, const float4* __restrict__ w4,
    float* __restrict__ out)
{
    extern __shared__ unsigned char smem[];
    half4v* lut = (half4v*)smem;

    const int tx = threadIdx.x;            // 0..63  (one wave = one ty row)
    const int ty = threadIdx.y;            // 0..15
    const int tid = ty * 64 + tx;
    const int x0 = (int)(blockIdx.x & 15) * TW;        // 16 x-strips
    const int y0 = (int)(blockIdx.x >> 4) * (TH * 4);  // 16 y-bands, 4 tiles
    // NB: vertically adjacent blocks (bid, bid+16) land on the same XCD under
    // the default %8 round-robin, so shared border rows are same-L2 hits.

    // 1) fp32 -> fp16 LUT into LDS (once per block)
    #pragma unroll
    for (int i = 0; i < 12; ++i) {
        int j = tid + i * 1024;
        float4 v = w4[j];
        half4v h;
        h.x = (_Float16)v.x; h.y = (_Float16)v.y;
        h.z = (_Float16)v.z; h.w = (_Float16)v.w;
        lut[j] = h;
    }
    __syncthreads();   // the ONLY barrier: after this, waves free-run

    const float s = 1.0f / 3.0f;
    fvec4* o4 = (fvec4*)out;

    // per-thread 6-col window [c0, c0+5]; int2 fast path unless it crosses
    // the image border (only lane 0 of strip 0 / lane 63 of strip 15)
    const int c0 = x0 + 2 * tx - 2;
    const bool fast = (c0 >= 0) && (c0 + 5 < N);

    #pragma unroll 1
    for (int t = 0; t < 4; ++t) {
        // 2) 6x6 neighborhood straight from global (L1-resident: a block's
        //    per-tile working set is 36 rows x 512 B = 18 KB)
        const int ybase = y0 + t * TH + 2 * ty;
        int n[6][6];
        #pragma unroll
        for (int r = 0; r < 6; ++r) {
            const int* row = img + reflect(ybase - 2 + r) * N;
            if (fast) {
                #pragma unroll
                for (int j = 0; j < 3; ++j) {
                    int2 t2 = *(const int2*)(row + c0 + 2 * j);
                    n[r][2 * j] = t2.x; n[r][2 * j + 1] = t2.y;
                }
            } else {
                #pragma unroll
                for (int j = 0; j < 6; ++j) n[r][j] = row[reflect(c0 + j)];
            }
        }

        float acc[2][2][4];
        #pragma unroll
        for (int i = 0; i < 2; ++i)
            #pragma unroll
            for (int j = 0; j < 2; ++j)
                #pragma unroll
                for (int c = 0; c < 4; ++c) acc[i][j][c] = 0.f;

        // 3) software-pipelined gathers: 4 groups of 12 (one per pixel),
        //    depth 2 in flight, consume one group behind issue
        {
            int idx[12];
            half4v vA[12], vB[12], vC[12], vD[12];

            calc_idx(n, 0, 0, idx);
            #pragma unroll
            for (int i = 0; i < 12; ++i) vA[i] = lut[idx[i]];
            __builtin_amdgcn_sched_group_barrier(0x100, 12, 0);

            calc_idx(n, 0, 1, idx);
            #pragma unroll
            for (int i = 0; i < 12; ++i) vB[i] = lut[idx[i]];
            __builtin_amdgcn_sched_group_barrier(0x100, 12, 0);

            consume(vA, acc[0][0]);

            calc_idx(n, 1, 0, idx);
            #pragma unroll
            for (int i = 0; i < 12; ++i) vC[i] = lut[idx[i]];
            __builtin_amdgcn_sched_group_barrier(0x100, 12, 0);

            consume(vB, acc[0][1]);

            calc_idx(n, 1, 1, idx);
            #pragma unroll
            for (int i = 0; i < 12; ++i) vD[i] = lut[idx[i]];
            __builtin_amdgcn_sched_group_barrier(0x100, 12, 0);

            consume(vC, acc[1][0]);
            consume(vD, acc[1][1]);
        }

        // 4) wave-contiguous non-temporal stores; no barrier follows, so the
        //    drain overlaps the next tile's loads/gathers naturally
        const int py = ybase;
        const int ox = (x0 + 2 * tx) * 2;
        {
            fvec4 v0 = {acc[0][0][0] * s, acc[0][0][1] * s, acc[0][1][0] * s, acc[0][1][1] * s};
            fvec4 v1 = {acc[0][0][2] * s, acc[0][0][3] * s, acc[0][1][2] * s, acc[0][1][3] * s};
            fvec4 v2 = {acc[1][0][0] * s, acc[1][0][1] * s, acc[1][1][0] * s, acc[1][1][1] * s};
            fvec4 v3 = {acc[1][0][2] * s, acc[1][0][3] * s, acc[1][1][2] * s, acc[1][1][3] * s};
            __builtin_nontemporal_store(v0, &o4[((2 * py + 0) * ONW + ox) >> 2]);
            __builtin_nontemporal_store(v1, &o4[((2 * py + 1) * ONW + ox) >> 2]);
            __builtin_nontemporal_store(v2, &o4[((2 * py + 2) * ONW + ox) >> 2]);
            __builtin_nontemporal_store(v3, &o4[((2 * py + 3) * ONW + ox) >> 2]);
        }
    }
}

extern "C" void kernel_launch(void* const* d_in, const int* in_sizes, int n_in,
                              void* d_out, int out_size, void* d_ws, size_t ws_size,
                              hipStream_t stream)
{
    const int* img = (const int*)d_in[0];
    const float4* w4 = (const float4*)d_in[1];
    float* out = (float*)d_out;
    (void)hipFuncSetAttribute(reinterpret_cast<const void*>(hdblut_kernel),
                              hipFuncAttributeMaxDynamicSharedMemorySize, SMEM_BYTES);
    hdblut_kernel<<<dim3(256), dim3(64, 16), SMEM_BYTES, stream>>>(img, w4, out);
}

// Round 7
// 102.108 us; speedup vs baseline: 1.0079x; 1.0079x over previous
//
#include <hip/hip_runtime.h>
#include <hip/hip_fp16.h>

#define N 2048
#define ONW 4096
#define TW 128                        // tile width (pixels)
#define TH 32                         // tile height (pixels)
#define LUT_ENTRIES 12288
#define LUT_BYTES (LUT_ENTRIES * 8)   // 98304
#define SMEM_BYTES LUT_BYTES          // LUT only

typedef _Float16 half4v __attribute__((ext_vector_type(4)));
typedef float fvec4 __attribute__((ext_vector_type(4)));
typedef float fvec2 __attribute__((ext_vector_type(2)));

__device__ __forceinline__ int reflect(int i) {
    i = i < 0 ? -i : i;
    return i >= N ? 2 * N - 2 - i : i;
}

// compute the 12 LUT indices for one output pixel (pi,pj); fully
// constant-folds when called with literal pi/pj under unrolled loops
__device__ __forceinline__ void calc_idx(const int n[6][6], int pi, int pj, int* idx)
{
    const int bo[3][2] = {{0, 1}, {1, 1}, {1, 2}};
    const int co[3][2] = {{0, 2}, {2, 2}, {2, 1}};
    const int a8 = n[2 + pi][2 + pj] << 8;
    #pragma unroll
    for (int r = 0; r < 4; ++r) {
        #pragma unroll
        for (int k = 0; k < 3; ++k) {
            const int bp = bo[k][0], bq = bo[k][1];
            const int cp = co[k][0], cq = co[k][1];
            const int bdi = (r == 0) ? bp : (r == 1) ? bq : (r == 2) ? -bp : -bq;
            const int bdj = (r == 0) ? bq : (r == 1) ? -bp : (r == 2) ? -bq : bp;
            const int cdi = (r == 0) ? cp : (r == 1) ? cq : (r == 2) ? -cp : -cq;
            const int cdj = (r == 0) ? cq : (r == 1) ? -cp : (r == 2) ? -cq : cp;
            const int bv = n[pi + 2 + bdi][pj + 2 + bdj];
            const int cv = n[pi + 2 + cdi][pj + 2 + cdj];
            idx[r * 3 + k] = (k * 4096 + a8) + (bv * 16 + cv);
        }
    }
}

// sum the 3 k-terms per rotation and scatter into the 2x2 sub-pixel acc
__device__ __forceinline__ void consume(const fvec2* v, float* o)
{
    #pragma unroll
    for (int r = 0; r < 4; ++r) {
        half4v S = __builtin_bit_cast(half4v, v[3 * r])
                 + __builtin_bit_cast(half4v, v[3 * r + 1])
                 + __builtin_bit_cast(half4v, v[3 * r + 2]);
        const float x = (float)S.x, y = (float)S.y;
        const float z = (float)S.z, w = (float)S.w;
        if (r == 0)      { o[0] += x; o[1] += y; o[2] += z; o[3] += w; }
        else if (r == 1) { o[0] += z; o[1] += x; o[2] += w; o[3] += y; }
        else if (r == 2) { o[0] += w; o[1] += z; o[2] += y; o[3] += x; }
        else             { o[0] += y; o[1] += w; o[2] += x; o[3] += z; }
    }
}

// waves_per_eu(4,4): dynamic LDS (98 KB) hides the 1-block/CU cap from the
// compiler, so by default it register-minimizes for an occupancy (8 w/EU,
// <=64 VGPR) that can never materialize, slicing our gather bursts into
// load->wait->consume chains (VGPR_Count was 44-48 every round). At the
// true 4 waves/EU, 128 VGPRs are free — let the scheduler use them.
__global__ __launch_bounds__(1024)
__attribute__((amdgpu_waves_per_eu(4, 4)))
void hdblut_kernel(
    const int* __restrict__ img, const float4* __restrict__ w4,
    float* __restrict__ out)
{
    extern __shared__ unsigned char smem[];
    half4v* lut = (half4v*)smem;
    const fvec2* lutf2 = (const fvec2*)smem;

    const int tx = threadIdx.x;            // 0..63  (one wave = one ty row)
    const int ty = threadIdx.y;            // 0..15
    const int tid = ty * 64 + tx;
    const int x0 = (int)(blockIdx.x & 15) * TW;        // 16 x-strips
    const int y0 = (int)(blockIdx.x >> 4) * (TH * 4);  // 16 y-bands, 4 tiles

    // 1) fp32 -> fp16 LUT into LDS (once per block)
    #pragma unroll
    for (int i = 0; i < 12; ++i) {
        int j = tid + i * 1024;
        float4 v = w4[j];
        half4v h;
        h.x = (_Float16)v.x; h.y = (_Float16)v.y;
        h.z = (_Float16)v.z; h.w = (_Float16)v.w;
        lut[j] = h;
    }
    __syncthreads();   // the ONLY barrier: after this, waves free-run

    const float s = 1.0f / 3.0f;
    fvec4* o4 = (fvec4*)out;

    // per-thread 6-col window [c0, c0+5]; int2 fast path unless it crosses
    // the image border (only lane 0 of strip 0 / lane 63 of strip 15)
    const int c0 = x0 + 2 * tx - 2;
    const bool fast = (c0 >= 0) && (c0 + 5 < N);

    #pragma unroll 1
    for (int t = 0; t < 4; ++t) {
        // 2) 6x6 neighborhood straight from global (L1/L2-resident)
        const int ybase = y0 + t * TH + 2 * ty;
        int n[6][6];
        #pragma unroll
        for (int r = 0; r < 6; ++r) {
            const int* row = img + reflect(ybase - 2 + r) * N;
            if (fast) {
                #pragma unroll
                for (int j = 0; j < 3; ++j) {
                    int2 t2 = *(const int2*)(row + c0 + 2 * j);
                    n[r][2 * j] = t2.x; n[r][2 * j + 1] = t2.y;
                }
            } else {
                #pragma unroll
                for (int j = 0; j < 6; ++j) n[r][j] = row[reflect(c0 + j)];
            }
        }

        // 3) ALL 48 indices first (n's last use — it dies here)
        int idx[48];
        calc_idx(n, 0, 0, idx);
        calc_idx(n, 0, 1, idx + 12);
        calc_idx(n, 1, 0, idx + 24);
        calc_idx(n, 1, 1, idx + 36);

        // 4) one 48-deep gather burst (96 result VGPRs), then ONE wait.
        //    The contiguous-issue request forces distinct dest registers —
        //    a single LDS-latency exposure per tile instead of dozens.
        fvec2 v[48];
        #pragma unroll
        for (int i = 0; i < 48; ++i) v[i] = lutf2[idx[i]];
        __builtin_amdgcn_sched_group_barrier(0x100, 48, 0);

        float acc[2][2][4];
        #pragma unroll
        for (int i = 0; i < 2; ++i)
            #pragma unroll
            for (int j = 0; j < 2; ++j)
                #pragma unroll
                for (int c = 0; c < 4; ++c) acc[i][j][c] = 0.f;

        consume(v,      acc[0][0]);
        consume(v + 12, acc[0][1]);
        consume(v + 24, acc[1][0]);
        consume(v + 36, acc[1][1]);

        // 5) wave-contiguous non-temporal stores; no barrier follows, so
        //    the drain overlaps the next tile's loads/gathers
        const int ox = (x0 + 2 * tx) * 2;
        {
            fvec4 v0 = {acc[0][0][0] * s, acc[0][0][1] * s, acc[0][1][0] * s, acc[0][1][1] * s};
            fvec4 v1 = {acc[0][0][2] * s, acc[0][0][3] * s, acc[0][1][2] * s, acc[0][1][3] * s};
            fvec4 v2 = {acc[1][0][0] * s, acc[1][0][1] * s, acc[1][1][0] * s, acc[1][1][1] * s};
            fvec4 v3 = {acc[1][0][2] * s, acc[1][0][3] * s, acc[1][1][2] * s, acc[1][1][3] * s};
            __builtin_nontemporal_store(v0, &o4[((2 * ybase + 0) * ONW + ox) >> 2]);
            __builtin_nontemporal_store(v1, &o4[((2 * ybase + 1) * ONW + ox) >> 2]);
            __builtin_nontemporal_store(v2, &o4[((2 * ybase + 2) * ONW + ox) >> 2]);
            __builtin_nontemporal_store(v3, &o4[((2 * ybase + 3) * ONW + ox) >> 2]);
        }
    }
}

extern "C" void kernel_launch(void* const* d_in, const int* in_sizes, int n_in,
                              void* d_out, int out_size, void* d_ws, size_t ws_size,
                              hipStream_t stream)
{
    const int* img = (const int*)d_in[0];
    const float4* w4 = (const float4*)d_in[1];
    float* out = (float*)d_out;
    (void)hipFuncSetAttribute(reinterpret_cast<const void*>(hdblut_kernel),
                              hipFuncAttributeMaxDynamicSharedMemorySize, SMEM_BYTES);
    hdblut_kernel<<<dim3(256), dim3(64, 16), SMEM_BYTES, stream>>>(img, w4, out);
}

// Round 8
// 102.034 us; speedup vs baseline: 1.0086x; 1.0007x over previous
//
#include <hip/hip_runtime.h>
#include <hip/hip_fp16.h>

#define N 2048
#define ONW 4096
#define TW 128                        // tile width (pixels)
#define TH 32                         // tile height (pixels)
#define LUT_ENTRIES 12288
#define LUT_BYTES (LUT_ENTRIES * 8)   // 98304
#define SMEM_BYTES LUT_BYTES          // LUT only

typedef _Float16 half4v __attribute__((ext_vector_type(4)));
typedef float fvec4 __attribute__((ext_vector_type(4)));
typedef float fvec2 __attribute__((ext_vector_type(2)));

__device__ __forceinline__ int reflect(int i) {
    i = i < 0 ? -i : i;
    return i >= N ? 2 * N - 2 - i : i;
}

// compute the 12 LUT indices for one output pixel (pi,pj); fully
// constant-folds when called with literal pi/pj under unrolled loops
__device__ __forceinline__ void calc_idx(const int n[6][6], int pi, int pj, int* idx)
{
    const int bo[3][2] = {{0, 1}, {1, 1}, {1, 2}};
    const int co[3][2] = {{0, 2}, {2, 2}, {2, 1}};
    const int a8 = n[2 + pi][2 + pj] << 8;
    #pragma unroll
    for (int r = 0; r < 4; ++r) {
        #pragma unroll
        for (int k = 0; k < 3; ++k) {
            const int bp = bo[k][0], bq = bo[k][1];
            const int cp = co[k][0], cq = co[k][1];
            const int bdi = (r == 0) ? bp : (r == 1) ? bq : (r == 2) ? -bp : -bq;
            const int bdj = (r == 0) ? bq : (r == 1) ? -bp : (r == 2) ? -bq : bp;
            const int cdi = (r == 0) ? cp : (r == 1) ? cq : (r == 2) ? -cp : -cq;
            const int cdj = (r == 0) ? cq : (r == 1) ? -cp : (r == 2) ? -cq : cp;
            const int bv = n[pi + 2 + bdi][pj + 2 + bdj];
            const int cv = n[pi + 2 + cdi][pj + 2 + cdj];
            idx[r * 3 + k] = (k * 4096 + a8) + (bv * 16 + cv);
        }
    }
}

// Issue 12 independent ds_read_b64 in ONE asm block: forces 24 distinct
// result VGPRs live (early-clobber) and 12 outstanding LGKM ops — the deep
// burst the compiler's pressure heuristic has refused to build for 7 rounds.
// LDS byte addr = idx*8: sole dynamic-LDS block => ABI base offset 0.
__device__ __forceinline__ void ds_issue12(const int* idx, fvec2* v)
{
    unsigned a0  = (unsigned)idx[0]  << 3, a1  = (unsigned)idx[1]  << 3,
             a2  = (unsigned)idx[2]  << 3, a3  = (unsigned)idx[3]  << 3,
             a4  = (unsigned)idx[4]  << 3, a5  = (unsigned)idx[5]  << 3,
             a6  = (unsigned)idx[6]  << 3, a7  = (unsigned)idx[7]  << 3,
             a8  = (unsigned)idx[8]  << 3, a9  = (unsigned)idx[9]  << 3,
             a10 = (unsigned)idx[10] << 3, a11 = (unsigned)idx[11] << 3;
    asm volatile(
        "ds_read_b64 %0, %12\n\t"
        "ds_read_b64 %1, %13\n\t"
        "ds_read_b64 %2, %14\n\t"
        "ds_read_b64 %3, %15\n\t"
        "ds_read_b64 %4, %16\n\t"
        "ds_read_b64 %5, %17\n\t"
        "ds_read_b64 %6, %18\n\t"
        "ds_read_b64 %7, %19\n\t"
        "ds_read_b64 %8, %20\n\t"
        "ds_read_b64 %9, %21\n\t"
        "ds_read_b64 %10, %22\n\t"
        "ds_read_b64 %11, %23\n\t"
        : "=&v"(v[0]), "=&v"(v[1]), "=&v"(v[2]),  "=&v"(v[3]),
          "=&v"(v[4]), "=&v"(v[5]), "=&v"(v[6]),  "=&v"(v[7]),
          "=&v"(v[8]), "=&v"(v[9]), "=&v"(v[10]), "=&v"(v[11])
        : "v"(a0), "v"(a1), "v"(a2),  "v"(a3), "v"(a4),  "v"(a5),
          "v"(a6), "v"(a7), "v"(a8),  "v"(a9), "v"(a10), "v"(a11));
}

// Counted wait: retire the OLDER group (12 newer reads stay in flight).
// DS ops complete in order, so lgkmcnt(12) == "group issued 2 blocks ago is
// done". The "+v" ties make every consumer data-depend on this asm, so
// consumes cannot be hoisted above the wait (rule-18 hazard closed).
__device__ __forceinline__ void ds_wait12(fvec2* v)
{
    asm volatile("s_waitcnt lgkmcnt(12)"
        : "+v"(v[0]), "+v"(v[1]), "+v"(v[2]),  "+v"(v[3]),
          "+v"(v[4]), "+v"(v[5]), "+v"(v[6]),  "+v"(v[7]),
          "+v"(v[8]), "+v"(v[9]), "+v"(v[10]), "+v"(v[11]));
}
__device__ __forceinline__ void ds_wait0(fvec2* v)
{
    asm volatile("s_waitcnt lgkmcnt(0)"
        : "+v"(v[0]), "+v"(v[1]), "+v"(v[2]),  "+v"(v[3]),
          "+v"(v[4]), "+v"(v[5]), "+v"(v[6]),  "+v"(v[7]),
          "+v"(v[8]), "+v"(v[9]), "+v"(v[10]), "+v"(v[11]));
}

// sum the 3 k-terms per rotation and scatter into the 2x2 sub-pixel acc
__device__ __forceinline__ void consume(const fvec2* v, float* o)
{
    #pragma unroll
    for (int r = 0; r < 4; ++r) {
        half4v S = __builtin_bit_cast(half4v, v[3 * r])
                 + __builtin_bit_cast(half4v, v[3 * r + 1])
                 + __builtin_bit_cast(half4v, v[3 * r + 2]);
        const float x = (float)S.x, y = (float)S.y;
        const float z = (float)S.z, w = (float)S.w;
        if (r == 0)      { o[0] += x; o[1] += y; o[2] += z; o[3] += w; }
        else if (r == 1) { o[0] += z; o[1] += x; o[2] += w; o[3] += y; }
        else if (r == 2) { o[0] += w; o[1] += z; o[2] += y; o[3] += x; }
        else             { o[0] += y; o[1] += w; o[2] += x; o[3] += z; }
    }
}

// waves_per_eu(4,4): LDS (98 KB) caps us at 1 block/CU = 4 waves/EU, where
// 128 VGPRs are free. Essential now: the asm-forced burst liveness (~124
// VGPR) must not be spilled by an RA targeting 8 waves/EU.
__global__ __launch_bounds__(1024)
__attribute__((amdgpu_waves_per_eu(4, 4)))
void hdblut_kernel(
    const int* __restrict__ img, const float4* __restrict__ w4,
    float* __restrict__ out)
{
    extern __shared__ unsigned char smem[];
    half4v* lut = (half4v*)smem;

    const int tx = threadIdx.x;            // 0..63  (one wave = one ty row)
    const int ty = threadIdx.y;            // 0..15
    const int tid = ty * 64 + tx;
    const int x0 = (int)(blockIdx.x & 15) * TW;        // 16 x-strips
    const int y0 = (int)(blockIdx.x >> 4) * (TH * 4);  // 16 y-bands, 4 tiles

    // 1) fp32 -> fp16 LUT into LDS (once per block)
    #pragma unroll
    for (int i = 0; i < 12; ++i) {
        int j = tid + i * 1024;
        float4 v = w4[j];
        half4v h;
        h.x = (_Float16)v.x; h.y = (_Float16)v.y;
        h.z = (_Float16)v.z; h.w = (_Float16)v.w;
        lut[j] = h;
    }
    __syncthreads();   // the ONLY barrier: after this, waves free-run

    const float s = 1.0f / 3.0f;
    fvec4* o4 = (fvec4*)out;

    // per-thread 6-col window [c0, c0+5]; int2 fast path unless it crosses
    // the image border (only lane 0 of strip 0 / lane 63 of strip 15)
    const int c0 = x0 + 2 * tx - 2;
    const bool fast = (c0 >= 0) && (c0 + 5 < N);

    #pragma unroll 1
    for (int t = 0; t < 4; ++t) {
        // 2) 6x6 neighborhood straight from global (L1/L2-resident)
        const int ybase = y0 + t * TH + 2 * ty;
        int n[6][6];
        #pragma unroll
        for (int r = 0; r < 6; ++r) {
            const int* row = img + reflect(ybase - 2 + r) * N;
            if (fast) {
                #pragma unroll
                for (int j = 0; j < 3; ++j) {
                    int2 t2 = *(const int2*)(row + c0 + 2 * j);
                    n[r][2 * j] = t2.x; n[r][2 * j + 1] = t2.y;
                }
            } else {
                #pragma unroll
                for (int j = 0; j < 6; ++j) n[r][j] = row[reflect(c0 + j)];
            }
        }

        float acc[2][2][4];
        #pragma unroll
        for (int i = 0; i < 2; ++i)
            #pragma unroll
            for (int j = 0; j < 2; ++j)
                #pragma unroll
                for (int c = 0; c < 4; ++c) acc[i][j][c] = 0.f;

        // 3) software pipeline, depth 2, explicit counted lgkmcnt waits:
        //    issue A, issue B, wait A (B in flight), consume A, issue C into
        //    A's regs, wait B, ... — exactly one group-latency exposed/tile.
        {
            int idx[12];
            fvec2 va[12], vb[12];

            calc_idx(n, 0, 0, idx);
            ds_issue12(idx, va);
            calc_idx(n, 0, 1, idx);
            ds_issue12(idx, vb);

            ds_wait12(va);
            consume(va, acc[0][0]);
            calc_idx(n, 1, 0, idx);
            ds_issue12(idx, va);

            ds_wait12(vb);
            consume(vb, acc[0][1]);
            calc_idx(n, 1, 1, idx);
            ds_issue12(idx, vb);

            ds_wait12(va);
            consume(va, acc[1][0]);

            ds_wait0(vb);
            consume(vb, acc[1][1]);
        }

        // 4) wave-contiguous non-temporal stores; no barrier follows, so
        //    the drain overlaps the next tile's loads/gathers
        const int ox = (x0 + 2 * tx) * 2;
        {
            fvec4 v0 = {acc[0][0][0] * s, acc[0][0][1] * s, acc[0][1][0] * s, acc[0][1][1] * s};
            fvec4 v1 = {acc[0][0][2] * s, acc[0][0][3] * s, acc[0][1][2] * s, acc[0][1][3] * s};
            fvec4 v2 = {acc[1][0][0] * s, acc[1][0][1] * s, acc[1][1][0] * s, acc[1][1][1] * s};
            fvec4 v3 = {acc[1][0][2] * s, acc[1][0][3] * s, acc[1][1][2] * s, acc[1][1][3] * s};
            __builtin_nontemporal_store(v0, &o4[((2 * ybase + 0) * ONW + ox) >> 2]);
            __builtin_nontemporal_store(v1, &o4[((2 * ybase + 1) * ONW + ox) >> 2]);
            __builtin_nontemporal_store(v2, &o4[((2 * ybase + 2) * ONW + ox) >> 2]);
            __builtin_nontemporal_store(v3, &o4[((2 * ybase + 3) * ONW + ox) >> 2]);
        }
    }
}

extern "C" void kernel_launch(void* const* d_in, const int* in_sizes, int n_in,
                              void* d_out, int out_size, void* d_ws, size_t ws_size,
                              hipStream_t stream)
{
    const int* img = (const int*)d_in[0];
    const float4* w4 = (const float4*)d_in[1];
    float* out = (float*)d_out;
    (void)hipFuncSetAttribute(reinterpret_cast<const void*>(hdblut_kernel),
                              hipFuncAttributeMaxDynamicSharedMemorySize, SMEM_BYTES);
    hdblut_kernel<<<dim3(256), dim3(64, 16), SMEM_BYTES, stream>>>(img, w4, out);
}

// Round 10
// 100.187 us; speedup vs baseline: 1.0272x; 1.0184x over previous
//
#include <hip/hip_runtime.h>
#include <hip/hip_fp16.h>

#define N 2048
#define ONW 4096
#define TW 128                        // tile width (pixels)
#define TH 32                         // tile height (pixels)
#define HW 132                        // halo tile width (ints)
#define HH 36                         // halo tile height
#define HELEMS (HW * HH)              // 4752
#define LUT_ENTRIES 12288
#define LUT_BYTES (LUT_ENTRIES * 8)   // 98304
#define NITEMS 512                    // 512 work items of 128x64 px (2 tiles)
#define SMEM_BYTES (LUT_BYTES + 2 * HELEMS * 4 + 16)  // 136336 <= 160K

typedef _Float16 half4v __attribute__((ext_vector_type(4)));
typedef float fvec4 __attribute__((ext_vector_type(4)));

__device__ __forceinline__ int reflect(int i) {
    i = i < 0 ? -i : i;
    return i >= N ? 2 * N - 2 - i : i;
}

// compute the 12 LUT indices for one output pixel (pi,pj); fully
// constant-folds when called with literal pi/pj under unrolled loops
__device__ __forceinline__ void calc_idx(const int n[6][6], int pi, int pj, int* idx)
{
    const int bo[3][2] = {{0, 1}, {1, 1}, {1, 2}};
    const int co[3][2] = {{0, 2}, {2, 2}, {2, 1}};
    const int a8 = n[2 + pi][2 + pj] << 8;
    #pragma unroll
    for (int r = 0; r < 4; ++r) {
        #pragma unroll
        for (int k = 0; k < 3; ++k) {
            const int bp = bo[k][0], bq = bo[k][1];
            const int cp = co[k][0], cq = co[k][1];
            const int bdi = (r == 0) ? bp : (r == 1) ? bq : (r == 2) ? -bp : -bq;
            const int bdj = (r == 0) ? bq : (r == 1) ? -bp : (r == 2) ? -bq : bp;
            const int cdi = (r == 0) ? cp : (r == 1) ? cq : (r == 2) ? -cp : -cq;
            const int cdj = (r == 0) ? cq : (r == 1) ? -cp : (r == 2) ? -cq : cp;
            const int bv = n[pi + 2 + bdi][pj + 2 + bdj];
            const int cv = n[pi + 2 + cdi][pj + 2 + cdj];
            idx[r * 3 + k] = (k * 4096 + a8) + (bv * 16 + cv);
        }
    }
}

// sum the 3 k-terms per rotation and scatter into the 2x2 sub-pixel acc
__device__ __forceinline__ void consume(const half4v* v, float* o)
{
    #pragma unroll
    for (int r = 0; r < 4; ++r) {
        half4v S = v[3 * r] + v[3 * r + 1] + v[3 * r + 2];
        const float x = (float)S.x, y = (float)S.y;
        const float z = (float)S.z, w = (float)S.w;
        if (r == 0)      { o[0] += x; o[1] += y; o[2] += z; o[3] += w; }
        else if (r == 1) { o[0] += z; o[1] += x; o[2] += w; o[3] += y; }
        else if (r == 2) { o[0] += w; o[1] += z; o[2] += y; o[3] += x; }
        else             { o[0] += y; o[1] += w; o[2] += x; o[3] += z; }
    }
}

// graph-capture-safe workspace init (kernel launches are always capturable;
// hipMemsetAsync inside kernel_launch is the prime suspect for R9's
// container failure)
__global__ void zero_counter(unsigned* __restrict__ c) { *c = 0u; }

// Work distribution: 256 blocks (1/CU) pull 512 items (128x64 px each)
// from a global atomic queue. Rationale: occupancy counters show the mean
// block finishes at ~56% of the wall — the kernel is straggler-bound
// (no rebalancing at 1 block/CU). Dynamic stealing lets fast CUs absorb
// the slow (data-dependent conflict/locality) regions.
__global__ __launch_bounds__(1024, 4) void hdblut_kernel(
    const int* __restrict__ img, const float4* __restrict__ w4,
    float* __restrict__ out, unsigned* __restrict__ cnt)
{
    extern __shared__ unsigned char smem[];
    half4v* lut = (half4v*)smem;
    int* bufs = (int*)(smem + LUT_BYTES);
    volatile int* s_item = (volatile int*)(smem + LUT_BYTES + 2 * HELEMS * 4);

    const int tx = threadIdx.x;            // 0..63  (one wave = one ty row)
    const int ty = threadIdx.y;            // 0..15
    const int tid = ty * 64 + tx;

    // 1) fp32 -> fp16 LUT into LDS (once per block)
    #pragma unroll
    for (int i = 0; i < 12; ++i) {
        int j = tid + i * 1024;
        float4 v = w4[j];
        half4v h;
        h.x = (_Float16)v.x; h.y = (_Float16)v.y;
        h.z = (_Float16)v.z; h.w = (_Float16)v.w;
        lut[j] = h;
    }
    __syncthreads();

    const float s = 1.0f / 3.0f;
    fvec4* o4 = (fvec4*)out;

    // bounded pull loop: even a corrupted counter cannot hang the kernel
    for (int pulls = 0; pulls < NITEMS; ++pulls) {
        int item;
        if (cnt != nullptr) {
            if (tid == 0) *s_item = (int)atomicAdd(cnt, 1u);
            __syncthreads();
            item = *s_item;
            __syncthreads();   // slot reusable; also fences prior tile reads
        } else {
            if (pulls >= 2) break;
            item = 2 * (int)blockIdx.x + pulls;
            __syncthreads();
        }
        if ((unsigned)item >= NITEMS) break;

        const int x0 = (item & 15) * TW;        // 16 x-strips
        const int y0 = (item >> 4) * (TH * 2);  // 32 y-stacks of 2 tiles

        // 2) tile 0 halo load (direct to LDS, bulk coalesced — cold-L2-safe)
        for (int e = tid; e < HELEMS; e += 1024) {
            int rr = e / HW, cc = e - rr * HW;
            bufs[e] = img[reflect(y0 + rr - 2) * N + reflect(x0 + cc - 2)];
        }
        __syncthreads();

        int pre[5];
        #pragma unroll 1
        for (int t = 0; t < 2; ++t) {
            int* cur = bufs + (t & 1) * HELEMS;
            int* nxt = bufs + ((t + 1) & 1) * HELEMS;

            // prefetch tile 1 into registers (latency hidden by compute)
            if (t < 1) {
                const int yb = y0 + TH;
                #pragma unroll
                for (int u = 0; u < 5; ++u) {
                    int e = tid + u * 1024;
                    if (e < HELEMS) {
                        int rr = e / HW, cc = e - rr * HW;
                        pre[u] = img[reflect(yb + rr - 2) * N + reflect(x0 + cc - 2)];
                    }
                }
            }

            // 3) 6x6 neighborhood for this thread's 2x2 pixel patch
            int n[6][6];
            {
                const int r0 = 2 * ty, c0 = 2 * tx;
                #pragma unroll
                for (int r = 0; r < 6; ++r)
                    #pragma unroll
                    for (int j = 0; j < 3; ++j) {
                        int2 t2 = *(const int2*)&cur[(r0 + r) * HW + c0 + 2 * j];
                        n[r][2 * j] = t2.x; n[r][2 * j + 1] = t2.y;
                    }
            }

            float acc[2][2][4];
            #pragma unroll
            for (int i = 0; i < 2; ++i)
                #pragma unroll
                for (int j = 0; j < 2; ++j)
                    #pragma unroll
                    for (int c = 0; c < 4; ++c) acc[i][j][c] = 0.f;

            // 4) software-pipelined gathers: 4 groups of 12 (one per pixel),
            //    depth 2 in flight, consume one group behind issue
            {
                int idx[12];
                half4v vA[12], vB[12], vC[12], vD[12];

                calc_idx(n, 0, 0, idx);
                #pragma unroll
                for (int i = 0; i < 12; ++i) vA[i] = lut[idx[i]];
                __builtin_amdgcn_sched_group_barrier(0x100, 12, 0);

                calc_idx(n, 0, 1, idx);
                #pragma unroll
                for (int i = 0; i < 12; ++i) vB[i] = lut[idx[i]];
                __builtin_amdgcn_sched_group_barrier(0x100, 12, 0);

                consume(vA, acc[0][0]);

                calc_idx(n, 1, 0, idx);
                #pragma unroll
                for (int i = 0; i < 12; ++i) vC[i] = lut[idx[i]];
                __builtin_amdgcn_sched_group_barrier(0x100, 12, 0);

                consume(vB, acc[0][1]);

                calc_idx(n, 1, 1, idx);
                #pragma unroll
                for (int i = 0; i < 12; ++i) vD[i] = lut[idx[i]];
                __builtin_amdgcn_sched_group_barrier(0x100, 12, 0);

                consume(vC, acc[1][0]);
                consume(vD, acc[1][1]);
            }

            // 5) wave-contiguous stores (1 KiB per wave per row)
            const int py = y0 + t * TH + 2 * ty;
            const int ox = (x0 + 2 * tx) * 2;
            {
                fvec4 v0 = {acc[0][0][0] * s, acc[0][0][1] * s, acc[0][1][0] * s, acc[0][1][1] * s};
                fvec4 v1 = {acc[0][0][2] * s, acc[0][0][3] * s, acc[0][1][2] * s, acc[0][1][3] * s};
                fvec4 v2 = {acc[1][0][0] * s, acc[1][0][1] * s, acc[1][1][0] * s, acc[1][1][1] * s};
                fvec4 v3 = {acc[1][0][2] * s, acc[1][0][3] * s, acc[1][1][2] * s, acc[1][1][3] * s};
                o4[((2 * py + 0) * ONW + ox) >> 2] = v0;
                o4[((2 * py + 1) * ONW + ox) >> 2] = v1;
                o4[((2 * py + 2) * ONW + ox) >> 2] = v2;
                o4[((2 * py + 3) * ONW + ox) >> 2] = v3;
            }

            // commit prefetched tile 1 to the other LDS buffer
            if (t < 1) {
                #pragma unroll
                for (int u = 0; u < 5; ++u) {
                    int e = tid + u * 1024;
                    if (e < HELEMS) nxt[e] = pre[u];
                }
                __syncthreads();
            }
        }
    }
}

extern "C" void kernel_launch(void* const* d_in, const int* in_sizes, int n_in,
                              void* d_out, int out_size, void* d_ws, size_t ws_size,
                              hipStream_t stream)
{
    const int* img = (const int*)d_in[0];
    const float4* w4 = (const float4*)d_in[1];
    float* out = (float*)d_out;
    unsigned* cnt = nullptr;
    if (d_ws != nullptr && ws_size >= sizeof(unsigned)) {
        cnt = (unsigned*)d_ws;
        zero_counter<<<dim3(1), dim3(1), 0, stream>>>(cnt);  // graph-safe init
    }
    (void)hipFuncSetAttribute(reinterpret_cast<const void*>(hdblut_kernel),
                              hipFuncAttributeMaxDynamicSharedMemorySize, SMEM_BYTES);
    hdblut_kernel<<<dim3(256), dim3(64, 16), SMEM_BYTES, stream>>>(img, w4, out, cnt);
}

// Round 11
// 92.156 us; speedup vs baseline: 1.1167x; 1.0872x over previous
//
#include <hip/hip_runtime.h>
#include <hip/hip_fp16.h>

#define N 2048
#define ONW 4096
#define TW 128                        // tile width (pixels)
#define TH 32                         // tile height (pixels)
#define HW 132                        // halo tile width (ints)
#define HH 36                         // halo tile height
#define HELEMS (HW * HH)              // 4752
#define LUT_ENTRIES 12288
#define LUT_BYTES (LUT_ENTRIES * 8)   // 98304
#define SMEM_BYTES (LUT_BYTES + 2 * HELEMS * 4)  // 136320 <= 160K

typedef _Float16 half4v __attribute__((ext_vector_type(4)));
typedef float fvec4 __attribute__((ext_vector_type(4)));

__device__ __forceinline__ int reflect(int i) {
    i = i < 0 ? -i : i;
    return i >= N ? 2 * N - 2 - i : i;
}

// compute the 12 LUT indices for one output pixel (pi,pj); fully
// constant-folds when called with literal pi/pj under unrolled loops
__device__ __forceinline__ void calc_idx(const int n[6][6], int pi, int pj, int* idx)
{
    const int bo[3][2] = {{0, 1}, {1, 1}, {1, 2}};
    const int co[3][2] = {{0, 2}, {2, 2}, {2, 1}};
    const int a8 = n[2 + pi][2 + pj] << 8;
    #pragma unroll
    for (int r = 0; r < 4; ++r) {
        #pragma unroll
        for (int k = 0; k < 3; ++k) {
            const int bp = bo[k][0], bq = bo[k][1];
            const int cp = co[k][0], cq = co[k][1];
            const int bdi = (r == 0) ? bp : (r == 1) ? bq : (r == 2) ? -bp : -bq;
            const int bdj = (r == 0) ? bq : (r == 1) ? -bp : (r == 2) ? -bq : bp;
            const int cdi = (r == 0) ? cp : (r == 1) ? cq : (r == 2) ? -cp : -cq;
            const int cdj = (r == 0) ? cq : (r == 1) ? -cp : (r == 2) ? -cq : cp;
            const int bv = n[pi + 2 + bdi][pj + 2 + bdj];
            const int cv = n[pi + 2 + cdi][pj + 2 + cdj];
            idx[r * 3 + k] = (k * 4096 + a8) + (bv * 16 + cv);
        }
    }
}

// sum the 3 k-terms per rotation and scatter into the 2x2 sub-pixel acc
__device__ __forceinline__ void consume(const half4v* v, float* o)
{
    #pragma unroll
    for (int r = 0; r < 4; ++r) {
        half4v S = v[3 * r] + v[3 * r + 1] + v[3 * r + 2];
        const float x = (float)S.x, y = (float)S.y;
        const float z = (float)S.z, w = (float)S.w;
        if (r == 0)      { o[0] += x; o[1] += y; o[2] += z; o[3] += w; }
        else if (r == 1) { o[0] += z; o[1] += x; o[2] += w; o[3] += y; }
        else if (r == 2) { o[0] += w; o[1] += z; o[2] += y; o[3] += x; }
        else             { o[0] += y; o[1] += w; o[2] += x; o[3] += z; }
    }
}

__global__ __launch_bounds__(1024, 4) void hdblut_kernel(
    const int* __restrict__ img, const float4* __restrict__ w4,
    float* __restrict__ out)
{
    extern __shared__ unsigned char smem[];
    half4v* lut = (half4v*)smem;
    int* bufs = (int*)(smem + LUT_BYTES);

    const int tx = threadIdx.x;            // 0..63  (one wave = one ty row)
    const int ty = threadIdx.y;            // 0..15
    const int tid = ty * 64 + tx;
    const int x0 = (int)(blockIdx.x & 15) * TW;        // 16 x-strips
    const int y0 = (int)(blockIdx.x >> 4) * (TH * 4);  // 16 y-bands, 4 tiles each

    // 1) fp32 -> fp16 LUT into LDS (once per block)
    #pragma unroll
    for (int i = 0; i < 12; ++i) {
        int j = tid + i * 1024;
        float4 v = w4[j];
        half4v h;
        h.x = (_Float16)v.x; h.y = (_Float16)v.y;
        h.z = (_Float16)v.z; h.w = (_Float16)v.w;
        lut[j] = h;
    }

    // 2) tile 0 halo load (direct to LDS)
    for (int e = tid; e < HELEMS; e += 1024) {
        int rr = e / HW, cc = e - rr * HW;
        bufs[e] = img[reflect(y0 + rr - 2) * N + reflect(x0 + cc - 2)];
    }
    __syncthreads();

    const float s = 1.0f / 3.0f;
    fvec4* o4 = (fvec4*)out;

    int pre[5];
    #pragma unroll 1
    for (int t = 0; t < 4; ++t) {
        int* cur = bufs + (t & 1) * HELEMS;
        int* nxt = bufs + ((t + 1) & 1) * HELEMS;

        // prefetch next tile into registers (latency hidden by compute)
        if (t < 3) {
            const int yb = y0 + (t + 1) * TH;
            #pragma unroll
            for (int u = 0; u < 5; ++u) {
                int e = tid + u * 1024;
                if (e < HELEMS) {
                    int rr = e / HW, cc = e - rr * HW;
                    pre[u] = img[reflect(yb + rr - 2) * N + reflect(x0 + cc - 2)];
                }
            }
        }

        // 3) 6x6 neighborhood for this thread's 2x2 pixel patch
        int n[6][6];
        {
            const int r0 = 2 * ty, c0 = 2 * tx;
            #pragma unroll
            for (int r = 0; r < 6; ++r)
                #pragma unroll
                for (int j = 0; j < 3; ++j) {
                    int2 t2 = *(const int2*)&cur[(r0 + r) * HW + c0 + 2 * j];
                    n[r][2 * j] = t2.x; n[r][2 * j + 1] = t2.y;
                }
        }

        float acc[2][2][4];
        #pragma unroll
        for (int i = 0; i < 2; ++i)
            #pragma unroll
            for (int j = 0; j < 2; ++j)
                #pragma unroll
                for (int c = 0; c < 4; ++c) acc[i][j][c] = 0.f;

        // 4) software-pipelined gathers: 4 groups of 12 (one per pixel),
        //    depth 2 in flight, consume one group behind issue
        {
            int idx[12];
            half4v vA[12], vB[12], vC[12], vD[12];

            calc_idx(n, 0, 0, idx);
            #pragma unroll
            for (int i = 0; i < 12; ++i) vA[i] = lut[idx[i]];
            __builtin_amdgcn_sched_group_barrier(0x100, 12, 0);

            calc_idx(n, 0, 1, idx);
            #pragma unroll
            for (int i = 0; i < 12; ++i) vB[i] = lut[idx[i]];
            __builtin_amdgcn_sched_group_barrier(0x100, 12, 0);

            consume(vA, acc[0][0]);

            calc_idx(n, 1, 0, idx);
            #pragma unroll
            for (int i = 0; i < 12; ++i) vC[i] = lut[idx[i]];
            __builtin_amdgcn_sched_group_barrier(0x100, 12, 0);

            consume(vB, acc[0][1]);

            calc_idx(n, 1, 1, idx);
            #pragma unroll
            for (int i = 0; i < 12; ++i) vD[i] = lut[idx[i]];
            __builtin_amdgcn_sched_group_barrier(0x100, 12, 0);

            consume(vC, acc[1][0]);
            consume(vD, acc[1][1]);
        }

        // 5) wave-contiguous non-temporal stores (out has zero reuse;
        //    bypass L2 so LUT/img stay resident)
        const int py = y0 + t * TH + 2 * ty;
        const int ox = (x0 + 2 * tx) * 2;
        {
            fvec4 v0 = {acc[0][0][0] * s, acc[0][0][1] * s, acc[0][1][0] * s, acc[0][1][1] * s};
            fvec4 v1 = {acc[0][0][2] * s, acc[0][0][3] * s, acc[0][1][2] * s, acc[0][1][3] * s};
            fvec4 v2 = {acc[1][0][0] * s, acc[1][0][1] * s, acc[1][1][0] * s, acc[1][1][1] * s};
            fvec4 v3 = {acc[1][0][2] * s, acc[1][0][3] * s, acc[1][1][2] * s, acc[1][1][3] * s};
            __builtin_nontemporal_store(v0, &o4[((2 * py + 0) * ONW + ox) >> 2]);
            __builtin_nontemporal_store(v1, &o4[((2 * py + 1) * ONW + ox) >> 2]);
            __builtin_nontemporal_store(v2, &o4[((2 * py + 2) * ONW + ox) >> 2]);
            __builtin_nontemporal_store(v3, &o4[((2 * py + 3) * ONW + ox) >> 2]);
        }

        // commit prefetched tile to the other LDS buffer
        if (t < 3) {
            #pragma unroll
            for (int u = 0; u < 5; ++u) {
                int e = tid + u * 1024;
                if (e < HELEMS) nxt[e] = pre[u];
            }
        }
        __syncthreads();
    }
}

extern "C" void kernel_launch(void* const* d_in, const int* in_sizes, int n_in,
                              void* d_out, int out_size, void* d_ws, size_t ws_size,
                              hipStream_t stream)
{
    const int* img = (const int*)d_in[0];
    const float4* w4 = (const float4*)d_in[1];
    float* out = (float*)d_out;
    (void)hipFuncSetAttribute(reinterpret_cast<const void*>(hdblut_kernel),
                              hipFuncAttributeMaxDynamicSharedMemorySize, SMEM_BYTES);
    hdblut_kernel<<<dim3(256), dim3(64, 16), SMEM_BYTES, stream>>>(img, w4, out);
}